// Round 1
// baseline (195.765 us; speedup 1.0000x reference)
//
#include <hip/hip_runtime.h>
#include <math.h>

#define GDIM 152
#define NA 3
#define GG (GDIM * GDIM)
#define EXP_CLAMP 1000.0f

__device__ __forceinline__ float sigmoidf(float v) {
    return 1.0f / (1.0f + __expf(-v));
}

__global__ __launch_bounds__(256) void yolo_decode_kernel(
    const float* __restrict__ x,
    const float* __restrict__ anchors,
    const int* __restrict__ img_size_p,
    float* __restrict__ out,
    int total)  // B * NA * G * G
{
    int idx = blockIdx.x * blockDim.x + threadIdx.x;
    if (idx >= total) return;

    float stride = (float)(*img_size_p) / (float)GDIM;  // 608/152 = 4.0

    int gx = idx % GDIM;
    int t1 = idx / GDIM;
    int gy = t1 % GDIM;
    int t2 = t1 / GDIM;        // t2 = b*NA + a
    int a  = t2 % NA;

    // input: x[b, a*12 + c, gy, gx] = x[(t2*12 + c)*GG + gy*G + gx]
    const float* ip = x + (size_t)t2 * 12 * GG + (size_t)gy * GDIM + gx;

    float p[12];
#pragma unroll
    for (int c = 0; c < 12; ++c) {
        p[c] = ip[(size_t)c * GG];
    }

    float inv_s = 1.0f / stride;
    float a_h = anchors[a * 5 + 0] * inv_s;
    float a_w = anchors[a * 5 + 1] * inv_s;
    float a_l = anchors[a * 5 + 2] * inv_s;

    float4 o0, o1, o2;
    o0.x = (sigmoidf(p[0]) + (float)gx) * stride;            // bx * stride
    o0.y = (sigmoidf(p[1]) + (float)gy) * stride;            // by * stride
    o0.z = sigmoidf(p[2]);                                   // bz
    o0.w = fminf(__expf(p[3]), EXP_CLAMP) * a_h * stride;    // bh * stride
    o1.x = fminf(__expf(p[4]), EXP_CLAMP) * a_w * stride;    // bw * stride
    o1.y = fminf(__expf(p[5]), EXP_CLAMP) * a_l * stride;    // bl * stride
    o1.z = p[6];                                             // im
    o1.w = p[7];                                             // re
    o2.x = sigmoidf(p[8]);                                   // conf
    o2.y = sigmoidf(p[9]);                                   // cls 0
    o2.z = sigmoidf(p[10]);                                  // cls 1
    o2.w = sigmoidf(p[11]);                                  // cls 2

    // output: out[idx*12 + k]; idx*48 bytes is 16B-aligned
    float4* op = (float4*)(out + (size_t)idx * 12);
    op[0] = o0;
    op[1] = o1;
    op[2] = o2;
}

extern "C" void kernel_launch(void* const* d_in, const int* in_sizes, int n_in,
                              void* d_out, int out_size, void* d_ws, size_t ws_size,
                              hipStream_t stream) {
    const float* x        = (const float*)d_in[0];
    const float* anchors  = (const float*)d_in[1];
    const int*   img_size = (const int*)d_in[2];
    float*       out      = (float*)d_out;

    const int B = 32;
    const int total = B * NA * GG;  // 2,217,984
    const int block = 256;
    const int grid = (total + block - 1) / block;

    yolo_decode_kernel<<<grid, block, 0, stream>>>(x, anchors, img_size, out, total);
}